// Round 5
// baseline (240.835 us; speedup 1.0000x reference)
//
#include <hip/hip_runtime.h>

#define BATCH 32
#define TT 8
#define VOCAB 2048
#define EMB 256
#define NG 8192          // 4*VOCAB
#define LAT 128
#define KTOT 2304        // EMB + VOCAB
#define NKT 72           // KTOT/32 k-tiles
#define NNT 512          // NG/16 n-tiles
#define KSPLIT 8
#define KT_PER 9         // NKT/KSPLIT

typedef __bf16 bf16x8 __attribute__((ext_vector_type(8)));
typedef float  f32x4  __attribute__((ext_vector_type(4)));

// ws layout (float offsets)
#define P_OFF   0
#define P_SZ    (KSPLIT*BATCH*NG)     // 2,097,152 f (8 MB)
#define H_OFF   (P_OFF + P_SZ)
#define H_SZ    (BATCH*VOCAB)
#define C_OFF   (H_OFF + H_SZ)
#define C_SZ    (BATCH*VOCAB)
#define ST_OFF  (C_OFF + C_SZ)
#define ST_SZ   (BATCH*8*2)
#define ESJ_OFF (ST_OFF + ST_SZ)
#define ESJ_SZ  32
#define AHB_OFF (ESJ_OFF + ESJ_SZ)    // ushort region: 32*2304 ushorts
#define AHB_SZF ((BATCH*KTOT)/2)      // 36864 floats
#define BP_OFF  (AHB_OFF + AHB_SZF)   // ushort region: 512*72*64*8 ushorts (~37.7MB)

__device__ __forceinline__ float sigmoidf_(float x){ return 1.f/(1.f+__expf(-x)); }
__device__ __forceinline__ float tanhf_(float x){
  x = fminf(fmaxf(x, -10.f), 10.f);
  float e = __expf(2.f*x);
  return (e-1.f)/(e+1.f);
}
__device__ __forceinline__ unsigned short f2bf(float f){   // round-to-nearest-even
  unsigned int u = __float_as_uint(f);
  return (unsigned short)((u + 0x7FFFu + ((u>>16)&1u)) >> 16);
}

// Init h/c=0, out[:,0,:]=0, Ahb = [bf16(E[tok[:,0]]) | zeros]
__global__ __launch_bounds__(256) void k_init(
    const int* __restrict__ tok, const float* __restrict__ E,
    float* __restrict__ h, float* __restrict__ c,
    unsigned short* __restrict__ Ahb, float* __restrict__ out){
  int i = blockIdx.x*256 + threadIdx.x;
  if (i < BATCH*VOCAB){ h[i] = 0.f; c[i] = 0.f; }
  if (i < BATCH*KTOT){
    int b = i / KTOT, k = i % KTOT;
    Ahb[i] = (k < EMB) ? f2bf(E[(size_t)tok[b*TT+0]*EMB + k]) : (unsigned short)0;
  }
  if (i < BATCH*LAT){
    int b = i >> 7, l = i & (LAT-1);
    out[(size_t)(b*TT + 0)*LAT + l] = 0.f;     // t=0: rng=0 -> z=0 exactly
  }
}

// One-time: pack [Wi;Wh] fp32 -> bf16 in MFMA B-operand fragment order.
// Bp[nt][kt][lane][j] = W[kt*32 + (lane>>4)*8 + j][nt*16 + (lane&15)]
__global__ __launch_bounds__(256) void k_pack_w(
    const float* __restrict__ Wi, const float* __restrict__ Wh,
    unsigned short* __restrict__ Bp){
  int g = blockIdx.x*256 + threadIdx.x;          // [0, 512*72*64)
  int lane = g & 63, kt = (g>>6) % NKT, nt = g / (64*NKT);
  int n = nt*16 + (lane & 15);
  int k0 = kt*32 + (lane>>4)*8;
  unsigned int u[4];
  #pragma unroll
  for (int p=0;p<4;p++){
    int ka = k0 + 2*p, kb = k0 + 2*p + 1;
    float fa = (ka < EMB) ? Wi[(size_t)ka*NG + n] : Wh[(size_t)(ka-EMB)*NG + n];
    float fb = (kb < EMB) ? Wi[(size_t)kb*NG + n] : Wh[(size_t)(kb-EMB)*NG + n];
    u[p] = (unsigned int)f2bf(fa) | ((unsigned int)f2bf(fb) << 16);
  }
  *(uint4*)&Bp[(size_t)g*8] = make_uint4(u[0],u[1],u[2],u[3]);
}

// P[kc] += [x|h](bf16) @ [Wi;Wh](bf16 packed) k-slice.  Plain stores, no atomics.
// Wave: M=32 x N=16 tile (2 MFMA/kt); block = 4 waves = 4 consecutive nt.
// Grid: (NNT/4=128, KSPLIT=8) = 1024 blocks -> 4 blocks/CU, 16 waves/CU.
// Designated block (0,0) also finalizes the PREVIOUS step's output (t>=2).
__global__ __launch_bounds__(256) void k_gemm(
    const unsigned short* __restrict__ Ahb, const unsigned short* __restrict__ Bp,
    float* __restrict__ P, const float* __restrict__ stats,
    const float* __restrict__ esj, float* __restrict__ out, int t){
  const int tid = threadIdx.x;

  if (blockIdx.x==0 && blockIdx.y==0 && t>=2){    // block-uniform branch
    __shared__ float vsh[BATCH];
    if (tid < BATCH){
      float Z=0.f, S=0.f;
      #pragma unroll
      for (int jc=0;jc<8;jc++){ Z += stats[(tid*8+jc)*2]; S += stats[(tid*8+jc)*2+1]; }
      vsh[tid] = (3.f*S + 1.5f*esj[tid])/Z;
    }
    __syncthreads();
    for (int i=tid; i<BATCH*LAT; i+=256)
      out[(size_t)((i>>7)*TT + (t-1))*LAT + (i&(LAT-1))] = vsh[i>>7];
  }

  const int w = tid >> 6, lane = tid & 63;
  const int quad = lane >> 4, col = lane & 15;
  const int nt  = blockIdx.x*4 + w;              // [0, 512)
  const int kc  = blockIdx.y;
  const int kt0 = kc*KT_PER;
  const bf16x8* __restrict__ AhV = (const bf16x8*)Ahb;  // idx m*288 + kt*4 + quad
  const bf16x8* __restrict__ BpV = (const bf16x8*)Bp;   // idx (nt*NKT+kt)*64 + lane

  f32x4 acc0={0,0,0,0}, acc1={0,0,0,0};
  const int a0b = col*(KTOT/8), a1b = (16+col)*(KTOT/8);
  #pragma unroll 3
  for (int kt = kt0; kt < kt0+KT_PER; kt++){
    bf16x8 b0 = BpV[(nt*NKT + kt)*64 + lane];
    bf16x8 a0 = AhV[a0b + kt*4 + quad];
    bf16x8 a1 = AhV[a1b + kt*4 + quad];
    acc0 = __builtin_amdgcn_mfma_f32_16x16x32_bf16(a0,b0,acc0,0,0,0);
    acc1 = __builtin_amdgcn_mfma_f32_16x16x32_bf16(a1,b0,acc1,0,0,0);
  }
  float* Pp = P + (size_t)kc*BATCH*NG;
  const int rowd = quad*4;
  #pragma unroll
  for (int r=0;r<4;r++){
    Pp[(size_t)(rowd+r)*NG    + nt*16 + col] = acc0[r];
    Pp[(size_t)(16+rowd+r)*NG + nt*16 + col] = acc1[r];
  }
}

// Reduce KSPLIT slabs + bias -> gates -> masked LSTM cell -> h,c -> bf16 h into
// Ahb; jc==0 blocks stage next step's x-row; partial softmax stats.
__global__ __launch_bounds__(256) void k_cellred(
    const int* __restrict__ tok, const float* __restrict__ E,
    const float* __restrict__ bias, const float* __restrict__ P,
    float* __restrict__ h, float* __restrict__ c, unsigned short* __restrict__ Ahb,
    float* __restrict__ stats, float* __restrict__ esj, int t){
  const int tid = threadIdx.x;
  const int jc = blockIdx.x, b = blockIdx.y;
  const int j = jc*256 + tid;
  const int lane = tid & 63, wid = tid >> 6;

  float ip = bias[j], fp = bias[j+VOCAB], gg = bias[j+2*VOCAB], op = bias[j+3*VOCAB];
  #pragma unroll
  for (int kc=0;kc<KSPLIT;kc++){
    const float* Pp = P + (size_t)(kc*BATCH + b)*NG;
    ip += Pp[j]; fp += Pp[j+VOCAB]; gg += Pp[j+2*VOCAB]; op += Pp[j+3*VOCAB];
  }

  float cold = c[b*VOCAB + j];
  float cn = sigmoidf_(fp)*cold + sigmoidf_(ip)*tanhf_(gg);
  float hn = sigmoidf_(op)*tanhf_(cn);
  const bool upd = tok[b*TT + (t-1)] != 0;
  float hf = upd ? hn : h[b*VOCAB + j];
  float cf = upd ? cn : cold;
  h[b*VOCAB + j] = hf;
  c[b*VOCAB + j] = cf;
  Ahb[b*KTOT + EMB + j] = f2bf(hf);
  if (jc == 0 && t < TT-1)   // stage next step's x-row: x = E[tok[:,t]]
    Ahb[b*KTOT + tid] = f2bf(E[(size_t)tok[b*TT + t]*EMB + tid]);

  const int sj = tok[b*TT + t];
  float e = __expf(hf);                 // h in (-1,1): no max-pass needed
  float z = e, s = (j < sj) ? e : 0.f;
  if (j == sj) esj[b] = e;

  __shared__ float zsh[4], ssh[4];
  #pragma unroll
  for (int off=32; off; off>>=1){ z += __shfl_down(z, off); s += __shfl_down(s, off); }
  if (lane==0){ zsh[wid] = z; ssh[wid] = s; }
  __syncthreads();
  if (tid==0){
    stats[(b*8 + jc)*2 + 0] = zsh[0]+zsh[1]+zsh[2]+zsh[3];
    stats[(b*8 + jc)*2 + 1] = ssh[0]+ssh[1]+ssh[2]+ssh[3];
  }
}

// z[b,t,:] = (3*S + 1.5*e_sj)/Z  broadcast over LAT  (final step)
__global__ __launch_bounds__(256) void k_out(
    const float* __restrict__ stats, const float* __restrict__ esj,
    float* __restrict__ out, int t){
  const int tid = threadIdx.x;
  __shared__ float vsh[BATCH];
  if (tid < BATCH){
    float Z=0.f, S=0.f;
    #pragma unroll
    for (int jc=0;jc<8;jc++){ Z += stats[(tid*8+jc)*2]; S += stats[(tid*8+jc)*2+1]; }
    vsh[tid] = (3.f*S + 1.5f*esj[tid])/Z;
  }
  __syncthreads();
  for (int i=tid; i<BATCH*LAT; i+=256)
    out[(size_t)((i>>7)*TT + t)*LAT + (i&(LAT-1))] = vsh[i>>7];
}

extern "C" void kernel_launch(void* const* d_in, const int* in_sizes, int n_in,
                              void* d_out, int out_size, void* d_ws, size_t ws_size,
                              hipStream_t stream){
  const int*   tok  = (const int*)d_in[0];
  const float* E    = (const float*)d_in[1];
  const float* Wi   = (const float*)d_in[2];
  const float* Wh   = (const float*)d_in[3];
  const float* bias = (const float*)d_in[4];
  float* out = (float*)d_out;
  float* ws  = (float*)d_ws;
  float* P     = ws + P_OFF;
  float* h     = ws + H_OFF;
  float* c     = ws + C_OFF;
  float* stats = ws + ST_OFF;
  float* esj   = ws + ESJ_OFF;
  unsigned short* Ahb = (unsigned short*)(ws + AHB_OFF);
  unsigned short* Bp  = (unsigned short*)(ws + BP_OFF);

  k_init<<<288, 256, 0, stream>>>(tok, E, h, c, Ahb, out);
  k_pack_w<<<(NNT*NKT*64)/256, 256, 0, stream>>>(Wi, Wh, Bp);
  for (int t = 1; t < TT; t++){
    k_gemm<<<dim3(NNT/4, KSPLIT), 256, 0, stream>>>(Ahb, Bp, P, stats, esj, out, t);
    k_cellred<<<dim3(8, BATCH), 256, 0, stream>>>(tok, E, bias, P, h, c, Ahb, stats, esj, t);
  }
  k_out<<<1, 256, 0, stream>>>(stats, esj, out, TT-1);
}